// Round 1
// 3014.654 us; speedup vs baseline: 1.8658x; 1.8658x over previous
//
#include <hip/hip_runtime.h>
#include <hip/hip_bf16.h>
#include <math.h>

#define HDIM 1024
#define BROWS 16384
#define TSTEPS 8
#define NCOLS 6144   // 1024 op1 | 1024 num1 | 4096 gates (16-col interleave r,z,in,hn)
#define CCOLS 2048   // C stores only the two GELU head blocks

typedef __bf16 bf16;
typedef __attribute__((ext_vector_type(8))) __bf16 bf16x8;
typedef __attribute__((ext_vector_type(4))) __bf16 bf16x4;
typedef __attribute__((ext_vector_type(4))) float f32x4;

__device__ __forceinline__ void async_ld16(void* lds, const void* g) {
  __builtin_amdgcn_global_load_lds((__attribute__((address_space(1))) void*)g,
                                   (__attribute__((address_space(3))) void*)lds,
                                   16, 0, 0);
}
__device__ __forceinline__ float gelu_exact(float x) {
  return 0.5f * x * (1.0f + erff(x * 0.70710678118654752f));
}
__device__ __forceinline__ float sigmoidf_(float x) {
  return 1.0f / (1.0f + __expf(-x));
}

// ---------------- weight prep ----------------
// Wcat[n][k] (bf16 row-major, k in [0,1024)):
//   n in [0,1024):    w_op1[k][n]        (transpose)
//   n in [1024,2048): w_num1[k][n-1024]  (transpose)
//   n in [2048,6144): gate region; n' = n-2048, g = n'>>6, sub = n'&63,
//                     kind = sub>>4, idx = g*16 + (sub&15):
//       kind0: w_ih[idx]+w_hh[idx] (r)   kind1: w_ih[1024+idx]+w_hh[1024+idx] (z)
//       kind2: w_ih[2048+idx] (i_n)      kind3: w_hh[2048+idx] (h_n)
__global__ void prep_trans(const float* __restrict__ w_op1, const float* __restrict__ w_num1,
                           bf16* __restrict__ Wcat) {
  __shared__ float tile[32][33];
  const float* src = blockIdx.z ? w_num1 : w_op1;
  const int cofs = blockIdx.z * 1024;
  const int kt = blockIdx.y * 32, nt = blockIdx.x * 32;
  const int tx = threadIdx.x, ty = threadIdx.y;  // 32 x 8
#pragma unroll
  for (int r = 0; r < 4; ++r) {
    int k = kt + ty + r * 8;
    tile[ty + r * 8][tx] = src[(size_t)k * HDIM + nt + tx];
  }
  __syncthreads();
#pragma unroll
  for (int r = 0; r < 4; ++r) {
    int n = nt + ty + r * 8;
    Wcat[(size_t)(cofs + n) * HDIM + kt + tx] = (bf16)tile[tx][ty + r * 8];
  }
}

__global__ void prep_gate(const float* __restrict__ w_ih, const float* __restrict__ w_hh,
                          bf16* __restrict__ Wcat) {
  const int np = blockIdx.x;   // 0..4095 output gate row
  const int k4 = threadIdx.x;  // 0..255 float4 within row
  const int g = np >> 6, sub = np & 63, kind = sub >> 4, idx = g * 16 + (sub & 15);
  const int r0 = (kind == 0) ? idx : (kind == 1) ? 1024 + idx : 2048 + idx;
  const float4* s1 = (const float4*)(w_ih + (size_t)r0 * HDIM);
  const float4* s2 = (const float4*)(w_hh + (size_t)r0 * HDIM);
  float4 v;
  if (kind <= 1) {
    float4 a = s1[k4], b = s2[k4];
    v.x = a.x + b.x; v.y = a.y + b.y; v.z = a.z + b.z; v.w = a.w + b.w;
  } else if (kind == 2) {
    v = s1[k4];
  } else {
    v = s2[k4];
  }
  bf16x4 o = {(bf16)v.x, (bf16)v.y, (bf16)v.z, (bf16)v.w};
  *(bf16x4*)(Wcat + (size_t)(2048 + np) * HDIM + k4 * 4) = o;
}

__global__ void prep_bias(const float* __restrict__ b_op1, const float* __restrict__ b_num1,
                          const float* __restrict__ b_ih, const float* __restrict__ b_hh,
                          float* __restrict__ bias) {
  int n = blockIdx.x * 256 + threadIdx.x;
  float v;
  if (n < 1024) v = b_op1[n];
  else if (n < 2048) v = b_num1[n - 1024];
  else {
    int np = n - 2048;
    int g = np >> 6, sub = np & 63, kind = sub >> 4, idx = g * 16 + (sub & 15);
    if (kind == 0) v = b_ih[idx] + b_hh[idx];
    else if (kind == 1) v = b_ih[1024 + idx] + b_hh[1024 + idx];
    else if (kind == 2) v = b_ih[2048 + idx];
    else v = b_hh[2048 + idx];
  }
  bias[n] = v;
}

__global__ void convert_x(const float* __restrict__ x, float* __restrict__ st0,
                          bf16* __restrict__ hbf) {
  size_t i = (size_t)blockIdx.x * 256 + threadIdx.x;  // over B*H/4
  float4 v = ((const float4*)x)[i];
  ((float4*)st0)[i] = v;
  bf16x4 b = {(bf16)v.x, (bf16)v.y, (bf16)v.z, (bf16)v.w};
  ((bf16x4*)hbf)[i] = b;
}

// ---------------- main GEMM + fused GRU epilogue ----------------
// 256x256 tile, BK=64, 8 waves (2Mx4N), 8-phase schedule, dbuf LDS (128KB),
// counted vmcnt(4) (never 0 in main loop), setprio around MFMA clusters.
// LDS: 16B chunks at physical (pr*8 + (c ^ (pr&7))); A/B rows physically
// permuted so each staged half-tile is contiguous:
//   A: pr = ((m&64)>>6)*128 + (m>>7)*64 + (m&63)   (A0 = rows used by Qa)
//   B: pr = ((n&32)>>5)*128 + (n>>6)*32 + (n&31)   (B0 = rows used by j=0,1)
#define MFMA_BLK(I0, J0)                                                       \
  _Pragma("unroll") for (int i_ = 0; i_ < 4; ++i_)                             \
  _Pragma("unroll") for (int j_ = 0; j_ < 2; ++j_)                             \
  _Pragma("unroll") for (int k_ = 0; k_ < 2; ++k_)                             \
  acc[(I0) + i_][(J0) + j_] = __builtin_amdgcn_mfma_f32_16x16x32_bf16(         \
      afr[i_][k_], bfr[(J0) + j_][k_], acc[(I0) + i_][(J0) + j_], 0, 0, 0);

__global__ void __launch_bounds__(512) gemm_step(
    const bf16* __restrict__ A,      // [chunk rows][1024] bf16 (h_t)
    const bf16* __restrict__ Bw,     // Wcat [6144][1024]
    const float* __restrict__ bias,  // [6144]
    const float* __restrict__ h_old, // [chunk rows][1024] f32 (h_t)
    float* __restrict__ h_new,       // [chunk rows][1024] f32 (h_{t+1})
    bf16* __restrict__ hbf_n,        // [chunk rows][1024] bf16 (h_{t+1})
    bf16* __restrict__ C,            // [chunk rows][2048] GELU head outputs
    int mt)                          // chunk/256
{
  __shared__ __align__(16) char smem[131072];
  bf16* const As0 = (bf16*)smem;
  bf16* const Bs0 = (bf16*)(smem + 32768);
  bf16* const As1 = (bf16*)(smem + 65536);
  bf16* const Bs1 = (bf16*)(smem + 98304);

  const int tid = threadIdx.x;
  const int wave = tid >> 6;
  const int lane = tid & 63;
  const int idx15 = lane & 15;
  const int quad = lane >> 4;
  const int wm = (wave >> 2) * 128;
  const int wn = (wave & 3) * 64;

  // XCD-bijective swizzle (gridDim.x always % 8 == 0 here); m-fast decompose.
  const int nwg = gridDim.x;
  const int cpx = nwg >> 3;
  const int wg = blockIdx.x;
  const int swz = (wg & 7) * cpx + (wg >> 3);
  const int tile_m = (swz % mt) * 256;
  const int tile_n = (swz / mt) * 256;

  // staging descriptors: half h, instr q -> 512 consecutive physical chunks
  const bf16* agp[2][2];
  const bf16* bgp[2][2];
  int lofs[2][2];
#pragma unroll
  for (int h = 0; h < 2; ++h)
#pragma unroll
    for (int q = 0; q < 2; ++q) {
      int p = h * 1024 + q * 512 + wave * 64 + lane;
      int pr = p >> 3;
      int c = (p & 7) ^ (pr & 7);
      int ma = ((pr >> 6) & 1) * 128 + (pr >> 7) * 64 + (pr & 63);
      int nb = ((pr >> 5) & 3) * 64 + (pr >> 7) * 32 + (pr & 31);
      agp[h][q] = A + (size_t)(tile_m + ma) * HDIM + c * 8;
      bgp[h][q] = Bw + (size_t)(tile_n + nb) * HDIM + c * 8;
      lofs[h][q] = (h * 1024 + q * 512 + wave * 64) * 8;
    }

  f32x4 acc[8][4] = {};
  bf16x8 afr[4][2], bfr[4][2];

  // prologue: stage tile 0 in need-order A0,B0,B1,A1; wait first two halves
  async_ld16(As0 + lofs[0][0], agp[0][0]);
  async_ld16(As0 + lofs[0][1], agp[0][1]);
  async_ld16(Bs0 + lofs[0][0], bgp[0][0]);
  async_ld16(Bs0 + lofs[0][1], bgp[0][1]);
  async_ld16(Bs0 + lofs[1][0], bgp[1][0]);
  async_ld16(Bs0 + lofs[1][1], bgp[1][1]);
  async_ld16(As0 + lofs[1][0], agp[1][0]);
  async_ld16(As0 + lofs[1][1], agp[1][1]);
  asm volatile("s_waitcnt vmcnt(4)" ::: "memory");
  __builtin_amdgcn_s_barrier();

  for (int t = 0; t < 16; ++t) {
    const int kn = ((t + 1) & 15) << 6;  // t=15 stages tile-0 garbage (never read)
    bf16* const Ac = (t & 1) ? As1 : As0;
    bf16* const Bc = (t & 1) ? Bs1 : Bs0;
    bf16* const An = (t & 1) ? As0 : As1;
    bf16* const Bn = (t & 1) ? Bs0 : Bs1;

    // ---- Qa: acc[0..3][0..1]; reads A0,B0; stages A0(t+1) ----
#pragma unroll
    for (int i = 0; i < 4; ++i) {
      int pr = (wm >> 1) + i * 16 + idx15;
#pragma unroll
      for (int k = 0; k < 2; ++k)
        afr[i][k] = *(const bf16x8*)&Ac[(pr * 8 + ((k * 4 + quad) ^ (pr & 7))) * 8];
    }
#pragma unroll
    for (int j = 0; j < 2; ++j) {
      int pr = (wn >> 1) + j * 16 + idx15;
#pragma unroll
      for (int k = 0; k < 2; ++k)
        bfr[j][k] = *(const bf16x8*)&Bc[(pr * 8 + ((k * 4 + quad) ^ (pr & 7))) * 8];
    }
    async_ld16(An + lofs[0][0], agp[0][0] + kn);
    async_ld16(An + lofs[0][1], agp[0][1] + kn);
    __builtin_amdgcn_s_barrier();
    __builtin_amdgcn_s_setprio(1);
    MFMA_BLK(0, 0)
    __builtin_amdgcn_s_setprio(0);
    asm volatile("s_waitcnt vmcnt(4)" ::: "memory");  // B1(t) landed
    __builtin_amdgcn_s_barrier();

    // ---- Qb: acc[0..3][2..3]; reads B1; stages B0(t+1) ----
#pragma unroll
    for (int j = 2; j < 4; ++j) {
      int pr = 128 + (wn >> 1) + (j & 1) * 16 + idx15;
#pragma unroll
      for (int k = 0; k < 2; ++k)
        bfr[j][k] = *(const bf16x8*)&Bc[(pr * 8 + ((k * 4 + quad) ^ (pr & 7))) * 8];
    }
    async_ld16(Bn + lofs[0][0], bgp[0][0] + kn);
    async_ld16(Bn + lofs[0][1], bgp[0][1] + kn);
    __builtin_amdgcn_s_barrier();
    __builtin_amdgcn_s_setprio(1);
    MFMA_BLK(0, 2)
    __builtin_amdgcn_s_setprio(0);
    asm volatile("s_waitcnt vmcnt(4)" ::: "memory");  // A1(t) landed
    __builtin_amdgcn_s_barrier();

    // ---- Qc: acc[4..7][0..1]; reads A1; stages B1(t+1) ----
#pragma unroll
    for (int i = 0; i < 4; ++i) {
      int pr = 128 + (wm >> 1) + i * 16 + idx15;
#pragma unroll
      for (int k = 0; k < 2; ++k)
        afr[i][k] = *(const bf16x8*)&Ac[(pr * 8 + ((k * 4 + quad) ^ (pr & 7))) * 8];
    }
    async_ld16(Bn + lofs[1][0], bgp[1][0] + kn);
    async_ld16(Bn + lofs[1][1], bgp[1][1] + kn);
    __builtin_amdgcn_s_barrier();
    __builtin_amdgcn_s_setprio(1);
    MFMA_BLK(4, 0)
    __builtin_amdgcn_s_setprio(0);
    __builtin_amdgcn_s_barrier();

    // ---- Qd: acc[4..7][2..3]; stages A1(t+1) ----
    async_ld16(An + lofs[1][0], agp[1][0] + kn);
    async_ld16(An + lofs[1][1], agp[1][1] + kn);
    __builtin_amdgcn_s_barrier();
    __builtin_amdgcn_s_setprio(1);
    MFMA_BLK(4, 2)
    __builtin_amdgcn_s_setprio(0);
    asm volatile("s_waitcnt vmcnt(4)" ::: "memory");  // A0,B0(t+1) landed
    __builtin_amdgcn_s_barrier();
  }

  asm volatile("s_waitcnt vmcnt(0)" ::: "memory");  // drain garbage stage
  __builtin_amdgcn_s_barrier();

  if (tile_n < 2048) {
    // ---- head tiles: bias + exact GELU, LDS-stage, full-line C writes ----
    bf16* Cs = (bf16*)smem;  // [256][256]
#pragma unroll
    for (int j = 0; j < 4; ++j) {
      float bv = bias[tile_n + wn + j * 16 + idx15];
#pragma unroll
      for (int i = 0; i < 8; ++i) {
#pragma unroll
        for (int rr = 0; rr < 4; ++rr) {
          int ml = wm + i * 16 + quad * 4 + rr;
          float v = acc[i][j][rr] + bv;
          Cs[ml * 256 + wn + j * 16 + idx15] = (bf16)gelu_exact(v);
        }
      }
    }
    __syncthreads();
#pragma unroll
    for (int it = 0; it < 16; ++it) {
      int idx = it * 512 + tid;
      int ml = idx >> 5, c8 = (idx & 31) << 3;
      bf16x8 v = *(const bf16x8*)&Cs[ml * 256 + c8];
      *(bf16x8*)&C[(size_t)(tile_m + ml) * CCOLS + tile_n + c8] = v;
    }
  } else {
    // ---- gate tiles: full GRU update fused; j-frags = {r, z, i_n, h_n} ----
    float* Hs = (float*)smem;            // [256][64] f32
    bf16* HBs = (bf16*)(smem + 65536);   // [256][64] bf16
    const int gb = (tile_n - 2048) >> 2;   // block gate base (64 gates/block)
    const int gl0 = wn >> 2;               // wave's gate offset in block
    const int n0 = tile_n + wn;
    const float br = bias[n0 + idx15];
    const float bz = bias[n0 + 16 + idx15];
    const float bi = bias[n0 + 32 + idx15];
    const float bh = bias[n0 + 48 + idx15];
    const int gate = gb + gl0 + idx15;
#pragma unroll
    for (int i = 0; i < 8; ++i) {
#pragma unroll
      for (int rr = 0; rr < 4; ++rr) {
        int ml = wm + i * 16 + quad * 4 + rr;
        size_t row = (size_t)(tile_m + ml);
        float rg = sigmoidf_(acc[i][0][rr] + br);
        float zg = sigmoidf_(acc[i][1][rr] + bz);
        float ng = tanhf(acc[i][2][rr] + bi + rg * (acc[i][3][rr] + bh));
        float h = h_old[row * HDIM + gate];
        float v = (1.0f - zg) * ng + zg * h;
        Hs[ml * 64 + gl0 + idx15] = v;
        HBs[ml * 64 + gl0 + idx15] = (bf16)v;
      }
    }
    __syncthreads();
#pragma unroll
    for (int it = 0; it < 8; ++it) {
      int idx = it * 512 + tid;
      int ml = idx >> 4, g4 = (idx & 15) << 2;
      float4 v = *(const float4*)&Hs[ml * 64 + g4];
      *(float4*)&h_new[(size_t)(tile_m + ml) * HDIM + gb + g4] = v;
    }
#pragma unroll
    for (int it = 0; it < 4; ++it) {
      int idx = it * 512 + tid;
      int ml = idx >> 3, g8 = (idx & 7) << 3;
      bf16x8 v = *(const bf16x8*)&HBs[ml * 64 + g8];
      *(bf16x8*)&hbf_n[(size_t)(tile_m + ml) * HDIM + gb + g8] = v;
    }
  }
}

// ---------------- per-step heads: ops[B,5], nums[B,1] ----------------
__global__ void __launch_bounds__(256) heads_step(
    const bf16* __restrict__ C, const float* __restrict__ w_op2,
    const float* __restrict__ b_op2, const float* __restrict__ w_num2,
    const float* __restrict__ b_num2, float* __restrict__ ops_t,
    float* __restrict__ nums_t, int row0) {
  const int wave = threadIdx.x >> 6;
  const int lane = threadIdx.x & 63;
  const int row = blockIdx.x * 4 + wave;
  const bf16* crow = C + (size_t)row * CCOLS;
  float a0 = 0, a1 = 0, a2 = 0, a3 = 0, a4 = 0, an = 0;
  for (int k = lane; k < HDIM; k += 64) {
    float hv = (float)crow[k];  // already GELU'd
    a0 += hv * w_op2[k * 5 + 0];
    a1 += hv * w_op2[k * 5 + 1];
    a2 += hv * w_op2[k * 5 + 2];
    a3 += hv * w_op2[k * 5 + 3];
    a4 += hv * w_op2[k * 5 + 4];
    an += (float)crow[HDIM + k] * w_num2[k];
  }
#pragma unroll
  for (int off = 32; off > 0; off >>= 1) {
    a0 += __shfl_down(a0, off);
    a1 += __shfl_down(a1, off);
    a2 += __shfl_down(a2, off);
    a3 += __shfl_down(a3, off);
    a4 += __shfl_down(a4, off);
    an += __shfl_down(an, off);
  }
  if (lane == 0) {
    size_t grow = (size_t)(row0 + row);
    ops_t[grow * 5 + 0] = a0 + b_op2[0];
    ops_t[grow * 5 + 1] = a1 + b_op2[1];
    ops_t[grow * 5 + 2] = a2 + b_op2[2];
    ops_t[grow * 5 + 3] = a3 + b_op2[3];
    ops_t[grow * 5 + 4] = a4 + b_op2[4];
    nums_t[grow] = an + b_num2[0];
  }
}

extern "C" void kernel_launch(void* const* d_in, const int* in_sizes, int n_in,
                              void* d_out, int out_size, void* d_ws, size_t ws_size,
                              hipStream_t stream) {
  const float* x      = (const float*)d_in[0];
  // d_in[1] = num_steps (always 8)
  const float* w_op1  = (const float*)d_in[2];
  const float* b_op1  = (const float*)d_in[3];
  const float* w_op2  = (const float*)d_in[4];
  const float* b_op2  = (const float*)d_in[5];
  const float* w_num1 = (const float*)d_in[6];
  const float* b_num1 = (const float*)d_in[7];
  const float* w_num2 = (const float*)d_in[8];
  const float* b_num2 = (const float*)d_in[9];
  const float* w_ih   = (const float*)d_in[10];
  const float* b_ih   = (const float*)d_in[11];
  const float* w_hh   = (const float*)d_in[12];
  const float* b_hh   = (const float*)d_in[13];

  float* out = (float*)d_out;
  float* final_state = out;                                  // [B,H]
  float* ops    = out + (size_t)BROWS * HDIM;                // [T,B,5]
  float* nums   = ops + (size_t)TSTEPS * BROWS * 5;          // [T,B,1]
  float* states = nums + (size_t)TSTEPS * BROWS;             // [T,B,H]

  char* ws = (char*)d_ws;
  bf16* Wcat  = (bf16*)ws;                                           // 12.6 MB
  float* bias = (float*)(ws + (size_t)NCOLS * HDIM * 2);             // 24 KB
  bf16* hbf0  = (bf16*)(ws + (size_t)NCOLS * HDIM * 2 + NCOLS * 4);  // 32 MB
  bf16* hbf1  = hbf0 + (size_t)BROWS * HDIM;                         // 32 MB
  char* cbase = (char*)(hbf1 + (size_t)BROWS * HDIM);
  bf16* C = (bf16*)cbase;
  size_t fixed = (size_t)(cbase - ws);

  int nch = 1;
  while (nch < 64 && fixed + (size_t)(BROWS / nch) * CCOLS * 2 > ws_size) nch *= 2;
  const int chunk = BROWS / nch;
  const int mt = chunk / 256;

  prep_trans<<<dim3(32, 32, 2), dim3(32, 8), 0, stream>>>(w_op1, w_num1, Wcat);
  prep_gate<<<4096, 256, 0, stream>>>(w_ih, w_hh, Wcat);
  prep_bias<<<NCOLS / 256, 256, 0, stream>>>(b_op1, b_num1, b_ih, b_hh, bias);
  convert_x<<<(BROWS * HDIM / 4) / 256, 256, 0, stream>>>(x, states, hbf0);

  for (int t = 0; t < TSTEPS; ++t) {
    float* st  = states + (size_t)t * BROWS * HDIM;
    float* stn = (t == TSTEPS - 1) ? final_state : states + (size_t)(t + 1) * BROWS * HDIM;
    float* ops_t  = ops + (size_t)t * BROWS * 5;
    float* nums_t = nums + (size_t)t * BROWS;
    const bf16* hin = (t & 1) ? hbf1 : hbf0;
    bf16* hout = (t & 1) ? hbf0 : hbf1;
    for (int c = 0; c < nch; ++c) {
      size_t r0 = (size_t)c * chunk;
      gemm_step<<<mt * (NCOLS / 256), 512, 0, stream>>>(
          hin + r0 * HDIM, Wcat, bias, st + r0 * HDIM, stn + r0 * HDIM,
          hout + r0 * HDIM, C, mt);
      heads_step<<<chunk / 4, 256, 0, stream>>>(C, w_op2, b_op2, w_num2, b_num2,
                                                ops_t, nums_t, (int)r0);
    }
  }
}